// Round 10
// baseline (158.295 us; speedup 1.0000x reference)
//
#include <hip/hip_runtime.h>

// CrossAttention with LoRA. B=16, C=64, hw=4096, L=77, COND=768, HEADS=8, dh=8.
// Round 11: 3 kernels -> 2. prep_weights eliminated:
//  - kvproj6: K/V from NATIVE Wk/Wv (per-chunk transpose through LDS, pad-65) with
//    LoRA via y = Wx + B(Ax) (reference's own factorization, no folded weights);
//    32 blocks fold Wq/Wo into ws as a tail (same kernel, no extra boundary).
//  - megattn: byte-identical r6 body (verified 50.0us).
// Rationale: r2 profile showed a dependent-boundary tax (~15-20us) charged to the
// consumer kernel (VALUBusy 0.07%, occ 0.07% window). Fewer boundaries = less tax.

#define HW   4096
#define CHN  64
#define LSEQ 77
#define CD   768
#define NB   16

// workspace float offsets
#define OFF_WQ 0
#define OFF_WO 102400
#define OFF_K  106496
#define OFF_V  185344

#define QF 0.51011784563163f  // SCALE * log2(e) = 8^-0.5 * 1.442695...

// K/V projection, self-contained. grid (308, 2 kv), block 256 = 4 waves.
// Tile = 4 rows x 64 co. Per 64-c chunk: stage W[64co][64c] -> wlds[c][co] (pad 65),
// then kvproj5 GEMM core (wave w owns c in [w*16,w*16+16), lane: l16 co-quad, cs c-phase).
// LoRA: ax[row][r] = A[r,:].x[row,:] (8-lane dots + shfl reduce); epilogue adds B.ax.
// Tail: blocks (x<32, kv==0) fold Wq/Wo -> ws (layout identical to old prep).
__global__ __launch_bounds__(256) void kvproj6(
    const float* __restrict__ cond,  // [1232][768]
    const float* __restrict__ Wk, const float* __restrict__ Ak, const float* __restrict__ Bk,
    const float* __restrict__ Wv, const float* __restrict__ Av, const float* __restrict__ Bv,
    const float* __restrict__ bk, const float* __restrict__ bv,
    const float* __restrict__ Wq, const float* __restrict__ Aq, const float* __restrict__ Bq,
    const float* __restrict__ Wo, const float* __restrict__ Ao, const float* __restrict__ Bo,
    float* __restrict__ ws) {
  __shared__ float xs[4 * CD];       // 12KB: x[4 rows][768]
  __shared__ float wlds[64 * 65];    // 16.25KB: transposed W chunk [c][co], pad 65
  __shared__ float red[16 * 256];    // 16KB: [group][row][co]
  __shared__ float axs[4 * 8];       // LoRA ax[row][r]
  int kv = blockIdx.y;
  int r0 = blockIdx.x * 4;           // 308*4 = 1232 exact
  int t  = threadIdx.x;
  int l  = t & 63;
  int w  = __builtin_amdgcn_readfirstlane(t >> 6);   // wave id
  int l16 = l & 15;
  int cs  = l >> 4;

  {
    const float4* src = (const float4*)(cond + r0 * CD);
    float4* dst = (float4*)xs;
    #pragma unroll
    for (int i = 0; i < 3; i++) dst[t + 256 * i] = src[t + 256 * i];  // 768 float4 exact
  }
  __syncthreads();

  // ---- LoRA ax: wave w = row w; r = (t>>3)&7; oct = t&7 covers c = oct+8i ----
  {
    int rr = (t >> 3) & 7;
    int oct = t & 7;
    const float* Arow = (kv ? Av : Ak) + rr * CD;
    const float* xrow = xs + w * CD;
    float part = 0.f;
    #pragma unroll 8
    for (int i = 0; i < 96; i++) part = fmaf(Arow[oct + 8 * i], xrow[oct + 8 * i], part);
    part += __shfl_xor(part, 1);
    part += __shfl_xor(part, 2);
    part += __shfl_xor(part, 4);
    if (oct == 0) axs[w * 8 + rr] = part;   // read after later barriers
  }

  // ---- main GEMM over 12 chunks of 64 c ----
  const float* Wsrc = kv ? Wv : Wk;        // [64 co][768 c] native
  float4 a0 = make_float4(0.f, 0.f, 0.f, 0.f);
  float4 a1 = a0, a2 = a0, a3 = a0;
  int co_s = t >> 2, q4 = t & 3;           // staging roles
  for (int ch = 0; ch < 12; ch++) {
    __syncthreads();                       // wlds safe to overwrite
    {
      const float* wp = Wsrc + co_s * CD + ch * 64 + q4 * 16;
      #pragma unroll
      for (int i = 0; i < 4; i++) {
        float4 wv4 = *(const float4*)(wp + 4 * i);
        wlds[(q4 * 16 + 4 * i + 0) * 65 + co_s] = wv4.x;
        wlds[(q4 * 16 + 4 * i + 1) * 65 + co_s] = wv4.y;
        wlds[(q4 * 16 + 4 * i + 2) * 65 + co_s] = wv4.z;
        wlds[(q4 * 16 + 4 * i + 3) * 65 + co_s] = wv4.w;
      }
    }
    __syncthreads();
    #pragma unroll
    for (int it = 0; it < 4; it++) {
      int c  = w * 16 + cs + 4 * it;       // chunk-local c
      int gc = ch * 64 + c;
      float4 wv = *(const float4*)(wlds + c * 65 + l16 * 4);
      float x0 = xs[0 * CD + gc];
      float x1 = xs[1 * CD + gc];
      float x2 = xs[2 * CD + gc];
      float x3 = xs[3 * CD + gc];
      a0.x = fmaf(x0, wv.x, a0.x); a0.y = fmaf(x0, wv.y, a0.y);
      a0.z = fmaf(x0, wv.z, a0.z); a0.w = fmaf(x0, wv.w, a0.w);
      a1.x = fmaf(x1, wv.x, a1.x); a1.y = fmaf(x1, wv.y, a1.y);
      a1.z = fmaf(x1, wv.z, a1.z); a1.w = fmaf(x1, wv.w, a1.w);
      a2.x = fmaf(x2, wv.x, a2.x); a2.y = fmaf(x2, wv.y, a2.y);
      a2.z = fmaf(x2, wv.z, a2.z); a2.w = fmaf(x2, wv.w, a2.w);
      a3.x = fmaf(x3, wv.x, a3.x); a3.y = fmaf(x3, wv.y, a3.y);
      a3.z = fmaf(x3, wv.z, a3.z); a3.w = fmaf(x3, wv.w, a3.w);
    }
  }
  {
    float4* redq = (float4*)(red + (w * 4 + cs) * 256);
    redq[0 * 16 + l16] = a0;
    redq[1 * 16 + l16] = a1;
    redq[2 * 16 + l16] = a2;
    redq[3 * 16 + l16] = a3;
  }
  __syncthreads();

  {
    int r  = t >> 6;                  // 4 rows x 64 co = 256 outputs exact
    int co = t & 63;
    float val = (kv ? bv : bk)[co];
    #pragma unroll
    for (int g = 0; g < 16; g++) val += red[g * 256 + r * 64 + co];
    const float* Bm = kv ? Bv : Bk;
    #pragma unroll
    for (int j = 0; j < 8; j++) val = fmaf(Bm[co * 8 + j], axs[r * 8 + j], val);
    (ws + (kv ? OFF_V : OFF_K))[(r0 + r) * 64 + co] = val;
  }

  // ---- tail: fold Wq (scaled by QF) and Wo into ws (prep-identical layout) ----
  if (kv == 0 && blockIdx.x < 32) {
    int idx = blockIdx.x * 256 + t;   // [0, 8192)
    const float *W, *A, *Bm;
    float* o;
    float scale;
    int local;
    if (idx < 4096) { W = Wq; A = Aq; Bm = Bq; o = ws + OFF_WQ; local = idx;        scale = QF;   }
    else            { W = Wo; A = Ao; Bm = Bo; o = ws + OFF_WO; local = idx - 4096; scale = 1.0f; }
    int co = local & 63;
    int c  = local >> 6;
    float val = W[co * 64 + c];
    #pragma unroll
    for (int r = 0; r < 8; r++) val += Bm[co * 8 + r] * A[r * 64 + c];
    o[local] = val * scale;           // local == c*64+co : W_eff^T [in][out]
  }
}

// Fused q-proj + attention + o-proj (byte-identical r6: 256 threads, 4 px/thread).
// grid (32 ptiles of 128, 16 b), block 256. h = t>>5, pl = t&31, 4 pixels/thread.
// qT never materialized; ao round-trips through LDS (stride-65 padding, 2-way conflict = free).
// Logits bounded => single-pass softmax with exp2 (wqT pre-scaled by SCALE*log2e).
__global__ __launch_bounds__(256, 2) void megattn(
    const float* __restrict__ z,     // [16][64][4096]
    const float* __restrict__ wqT,   // [64][64] (pre-scaled by QF)
    const float* __restrict__ bq,
    const float* __restrict__ kbuf,  // [16][77][64]
    const float* __restrict__ vbuf,
    const float* __restrict__ woT,   // [64][64]
    const float* __restrict__ bo,
    float* __restrict__ out) {       // [16][64][4096]
  __shared__ float smem[LSEQ * 64 * 2];   // 9856 floats: k|v ; later reused as ao[128][65]
  int b  = blockIdx.y;
  int p0 = blockIdx.x * 128;
  int t  = threadIdx.x;
  int h  = t >> 5;
  int pl = t & 31;

  float* ks = smem;
  float* vs = smem + LSEQ * 64;
  {
    const float4* ksrc = (const float4*)(kbuf + b * LSEQ * 64);
    const float4* vsrc = (const float4*)(vbuf + b * LSEQ * 64);
    float4* kd = (float4*)ks;
    float4* vd = (float4*)vs;
    for (int i = t; i < LSEQ * 16; i += 256) { kd[i] = ksrc[i]; vd[i] = vsrc[i]; }
  }

  // ---- Q phase: q[p][8h..8h+7] for p = p0 + pl + 32*i, i<4 (runs before the barrier) ----
  float qr[4][8];
  {
    const float4 b0 = *(const float4*)(bq + 8 * h);
    const float4 b1 = *(const float4*)(bq + 8 * h + 4);
    #pragma unroll
    for (int i = 0; i < 4; i++) {
      qr[i][0] = b0.x * QF; qr[i][1] = b0.y * QF; qr[i][2] = b0.z * QF; qr[i][3] = b0.w * QF;
      qr[i][4] = b1.x * QF; qr[i][5] = b1.y * QF; qr[i][6] = b1.z * QF; qr[i][7] = b1.w * QF;
    }
  }
  const float* zb = z + b * (CHN * HW) + p0 + pl;
  #pragma unroll 4
  for (int c = 0; c < 64; c++) {
    float4 w0 = *(const float4*)(wqT + c * 64 + 8 * h);
    float4 w1 = *(const float4*)(wqT + c * 64 + 8 * h + 4);
    float zv[4];
    #pragma unroll
    for (int i = 0; i < 4; i++) zv[i] = zb[c * HW + 32 * i];
    #pragma unroll
    for (int i = 0; i < 4; i++) {
      qr[i][0] = fmaf(zv[i], w0.x, qr[i][0]);
      qr[i][1] = fmaf(zv[i], w0.y, qr[i][1]);
      qr[i][2] = fmaf(zv[i], w0.z, qr[i][2]);
      qr[i][3] = fmaf(zv[i], w0.w, qr[i][3]);
      qr[i][4] = fmaf(zv[i], w1.x, qr[i][4]);
      qr[i][5] = fmaf(zv[i], w1.y, qr[i][5]);
      qr[i][6] = fmaf(zv[i], w1.z, qr[i][6]);
      qr[i][7] = fmaf(zv[i], w1.w, qr[i][7]);
    }
  }
  __syncthreads();

  // ---- Attention phase ----
  float acc[4][8];
  float li[4];
  #pragma unroll
  for (int i = 0; i < 4; i++) {
    li[i] = 0.f;
    #pragma unroll
    for (int d = 0; d < 8; d++) acc[i][d] = 0.f;
  }
  #pragma unroll 2
  for (int j = 0; j < LSEQ; j++) {
    float4 k0 = *(const float4*)(ks + j * 64 + 8 * h);
    float4 k1 = *(const float4*)(ks + j * 64 + 8 * h + 4);
    float4 v0 = *(const float4*)(vs + j * 64 + 8 * h);
    float4 v1 = *(const float4*)(vs + j * 64 + 8 * h + 4);
    #pragma unroll
    for (int i = 0; i < 4; i++) {
      float s = qr[i][0] * k0.x;
      s = fmaf(qr[i][1], k0.y, s);
      s = fmaf(qr[i][2], k0.z, s);
      s = fmaf(qr[i][3], k0.w, s);
      s = fmaf(qr[i][4], k1.x, s);
      s = fmaf(qr[i][5], k1.y, s);
      s = fmaf(qr[i][6], k1.z, s);
      s = fmaf(qr[i][7], k1.w, s);
      float e = __builtin_amdgcn_exp2f(s);
      li[i] += e;
      acc[i][0] = fmaf(e, v0.x, acc[i][0]);
      acc[i][1] = fmaf(e, v0.y, acc[i][1]);
      acc[i][2] = fmaf(e, v0.z, acc[i][2]);
      acc[i][3] = fmaf(e, v0.w, acc[i][3]);
      acc[i][4] = fmaf(e, v1.x, acc[i][4]);
      acc[i][5] = fmaf(e, v1.y, acc[i][5]);
      acc[i][6] = fmaf(e, v1.z, acc[i][6]);
      acc[i][7] = fmaf(e, v1.w, acc[i][7]);
    }
  }
  __syncthreads();   // all k/v reads done; smem reusable

  // ---- ao -> LDS, layout [128][65] (stride 65: 2 lanes/bank = free) ----
  float* ao = smem;
  #pragma unroll
  for (int i = 0; i < 4; i++) {
    float inv = 1.0f / li[i];
    int p = pl + 32 * i;
    #pragma unroll
    for (int d = 0; d < 8; d++) ao[p * 65 + 8 * h + d] = acc[i][d] * inv;
  }
  __syncthreads();

  // ---- O phase: out[p][co] = ao[p] . woT[:,co] + bo ----
  int q2 = t & 127;
  int chalf = __builtin_amdgcn_readfirstlane((t >> 7) & 1);  // wave-uniform -> scalar weight loads
  float acc2[32];
  #pragma unroll
  for (int j2 = 0; j2 < 32; j2++) acc2[j2] = bo[chalf * 32 + j2];
  const float* aor = ao + q2 * 65;
  #pragma unroll 4
  for (int c = 0; c < 64; c++) {
    float xv = aor[c];
    const float* wr = woT + c * 64 + chalf * 32;
    #pragma unroll
    for (int j2 = 0; j2 < 32; j2++) acc2[j2] = fmaf(xv, wr[j2], acc2[j2]);
  }
  float* ob = out + b * (CHN * HW) + p0 + q2;
  #pragma unroll
  for (int j2 = 0; j2 < 32; j2++) ob[(chalf * 32 + j2) * HW] = acc2[j2];
}

extern "C" void kernel_launch(void* const* d_in, const int* in_sizes, int n_in,
                              void* d_out, int out_size, void* d_ws, size_t ws_size,
                              hipStream_t stream) {
  const float* z    = (const float*)d_in[0];
  const float* cond = (const float*)d_in[1];
  const float* Wq = (const float*)d_in[2];  const float* bq = (const float*)d_in[3];
  const float* Aq = (const float*)d_in[4];  const float* Bq = (const float*)d_in[5];
  const float* Wk = (const float*)d_in[6];  const float* bk = (const float*)d_in[7];
  const float* Ak = (const float*)d_in[8];  const float* Bk = (const float*)d_in[9];
  const float* Wv = (const float*)d_in[10]; const float* bv = (const float*)d_in[11];
  const float* Av = (const float*)d_in[12]; const float* Bv = (const float*)d_in[13];
  const float* Wo = (const float*)d_in[14]; const float* bo = (const float*)d_in[15];
  const float* Ao = (const float*)d_in[16]; const float* Bo = (const float*)d_in[17];
  float* ws  = (float*)d_ws;
  float* out = (float*)d_out;

  kvproj6<<<dim3(308, 2), 256, 0, stream>>>(cond, Wk, Ak, Bk, Wv, Av, Bv, bk, bv,
                                            Wq, Aq, Bq, Wo, Ao, Bo, ws);
  megattn<<<dim3(32, 16), 256, 0, stream>>>(z, ws + OFF_WQ, bq, ws + OFF_K, ws + OFF_V,
                                            ws + OFF_WO, bo, out);
}